// Round 3
// baseline (1470.823 us; speedup 1.0000x reference)
//
#include <hip/hip_runtime.h>

// CTRNN: T=512, B=256, I=64, H=256.
//   pre = x_t @ W_in^T + b_in + h @ W_hh^T + b_hh + noise_t
//   h   = max(0.8*h + 0.2*pre, 0)
//
// R1 post-mortem: fusing W_in into the recurrence pushed live regs to ~120;
// compiler allocated only 64 VGPRs -> weight demotion -> ~2x VALU inflation
// (VALUBusy 59% of 699us vs ~190us source-level issue). Fix: two kernels,
// 64 weight floats/thread MAX in each.
// R2: infra failure ("container failed twice") -- identical resubmission.
//
//  K1 ctrnn_prex2: prex[p,j] = x[p,:]&W_in[j,:] + b_in[j]+b_hh[j]+noise[t,j]
//     1024 blocks x 256 thr; W_in row in 64 regs; x staged in 32-pair LDS
//     chunks -> 8 barriers/block total (old prex: 128 -> 237us; floor ~35us).
//  K2 ctrnn_rec2: R1's field-verified structure minus the W_in fusion:
//     - wave g owns h rows [16g,16g+16) AND k-chunk [16g,16g+16) -> h is
//       wave-private, no barrier needed for it.
//     - ONE barrier/step: lgkmcnt(0)-only asm barrier (global prefetches and
//       out stores stay in flight across it; __syncthreads would vmcnt-drain).
//     - pbuf double-buffered (stride 264: 2-way max on reduce reads = free).
//     - 64-lane spread reduce: 4 LDS reads + 2 shfl_xor.
//     - weights w[4][16] = 64 floats, FULLY const-indexed.

#define T_STEPS 512
#define BATCH   256
#define INSZ    64
#define HID     256
#define ALPHA_F 0.2f
#define OMA_F   0.8f

// ---------------------------------------------------------------------------
// Kernel 1: prex = x @ W_in^T + b_in + b_hh + noise(t)   [biases folded]
// 1024 blocks x 256 threads; block bb owns pairs [128*bb, 128*bb+128),
// t = (128*bb)>>8 is FIXED per block -> bias+noise folded once.
// ---------------------------------------------------------------------------
__global__ __launch_bounds__(256, 4)
void ctrnn_prex2(const float* __restrict__ x,      // [T, B, I]
                 const float* __restrict__ noise,  // [T, H]
                 const float* __restrict__ W_in,   // [H, I]
                 const float* __restrict__ b_in,   // [H]
                 const float* __restrict__ b_hh,   // [H]
                 float* __restrict__ prex)         // [T, B, H] (ws)
{
    const int j  = threadIdx.x;          // output column 0..255
    const int bb = blockIdx.x;           // 0..1023
    const int p0 = bb * 128;
    const int t  = p0 >> 8;              // fixed per block

    __shared__ __align__(16) float xs[2][32][INSZ];   // 16 KB double-buffered

    float w[INSZ];
#pragma unroll
    for (int k = 0; k < INSZ; k += 4) {
        float4 v = *reinterpret_cast<const float4*>(&W_in[j * INSZ + k]);
        w[k] = v.x; w[k+1] = v.y; w[k+2] = v.z; w[k+3] = v.w;
    }
    const float bias = b_in[j] + b_hh[j] + noise[t * HID + j];

    // stage chunk 0: 32 pairs x 64 floats = 512 float4, 2 per thread, coalesced
    {
        const float4* s4 = reinterpret_cast<const float4*>(&x[(size_t)p0 * INSZ]);
        float4* d4 = reinterpret_cast<float4*>(&xs[0][0][0]);
        d4[j] = s4[j]; d4[j + 256] = s4[j + 256];
    }
    __syncthreads();

#pragma unroll 1
    for (int c = 0; c < 4; ++c) {
        const int cur = c & 1;

        // T14 split: issue next chunk's global loads now, LDS-write after compute
        float4 st0 = make_float4(0.f,0.f,0.f,0.f), st1 = st0;
        if (c < 3) {
            const float4* s4 = reinterpret_cast<const float4*>(
                &x[(size_t)(p0 + (c + 1) * 32) * INSZ]);
            st0 = s4[j]; st1 = s4[j + 256];
        }

        float* op = &prex[(size_t)(p0 + c * 32) * HID + j];
#pragma unroll 2
        for (int pp = 0; pp < 32; ++pp) {
            float a0 = 0.f, a1 = 0.f, a2 = 0.f, a3 = 0.f;
#pragma unroll
            for (int k = 0; k < INSZ; k += 4) {   // FULL unroll: w[] const-indexed
                float4 xv = *reinterpret_cast<const float4*>(&xs[cur][pp][k]);
                a0 = fmaf(w[k],     xv.x, a0);
                a1 = fmaf(w[k + 1], xv.y, a1);
                a2 = fmaf(w[k + 2], xv.z, a2);
                a3 = fmaf(w[k + 3], xv.w, a3);
            }
            op[(size_t)pp * HID] = (a0 + a1) + (a2 + a3) + bias;   // coalesced
        }

        if (c < 3) {
            float4* d4 = reinterpret_cast<float4*>(&xs[cur ^ 1][0][0]);
            d4[j] = st0; d4[j + 256] = st1;
        }
        __syncthreads();
    }
}

// ---------------------------------------------------------------------------
// Kernel 2: the recurrence. 256 blocks x 1024 threads (16 waves, 4/SIMD).
// ---------------------------------------------------------------------------
__global__ __launch_bounds__(1024, 4)
void ctrnn_rec2(const float* __restrict__ hidden,  // [B, H]
                const float* __restrict__ prex,    // [T, B, H] (ws, biases in)
                const float* __restrict__ W_hh,    // [H, H]
                float* __restrict__ out)           // [T,B,H] ++ [B,H]
{
    const int tid  = threadIdx.x;
    const int lane = tid & 63;
    const int g    = tid >> 6;           // wave 0..15: rows & k-chunk [16g,16g+16)
    const int b    = blockIdx.x;

    __shared__ __align__(16) float hbuf[HID];
    __shared__ __align__(16) float pbuf[2][16 * 264];  // [buf][gg*264 + m*64 + jj]

    // W_hh: 4 rows x 16 k = 64 floats, FULLY const-indexed.
    float w[4][16];
#pragma unroll
    for (int m = 0; m < 4; ++m) {
        const float* wr = &W_hh[(lane + 64 * m) * HID + 16 * g];
#pragma unroll
        for (int c = 0; c < 4; ++c) {
            float4 v = *reinterpret_cast<const float4*>(&wr[4 * c]);
            w[m][4*c]   = v.x; w[m][4*c+1] = v.y;
            w[m][4*c+2] = v.z; w[m][4*c+3] = v.w;
        }
    }

    const int rrow = 16 * g + (lane & 15);   // row this lane reduces/updates
    float hj = hidden[b * HID + rrow];

    // prex pointer chain, 2-deep prefetch (all 64 lanes replicated x4 by q).
    const float* pp = &prex[(size_t)b * HID + rrow];
    float pcur = pp[0];                       // t = 0
    float pn1  = pp[BATCH * HID];             // t = 1
    pp += 2 * (size_t)BATCH * HID;
    float* op = &out[(size_t)b * HID + rrow];

    if (lane < 16) hbuf[rrow] = hj;           // wave-private h init
    __syncthreads();

    const int redoff = ((g >> 2) << 6) + ((g & 3) << 4) + (lane & 15);
    const int q = lane >> 4;

#pragma unroll 1
    for (int t = 0; t < T_STEPS; ++t) {
        const int cur = t & 1;

        // prefetch prex(t+2): stays in flight across the lgkm-only barrier
        float pn2 = 0.f;
        if (t + 2 < T_STEPS) pn2 = pp[0];
        pp += (size_t)BATCH * HID;

        // ---- FMA phase: h chunk is wave-private (written last step) ----
        const float4 h0 = *reinterpret_cast<const float4*>(&hbuf[16 * g]);
        const float4 h1 = *reinterpret_cast<const float4*>(&hbuf[16 * g + 4]);
        const float4 h2 = *reinterpret_cast<const float4*>(&hbuf[16 * g + 8]);
        const float4 h3 = *reinterpret_cast<const float4*>(&hbuf[16 * g + 12]);

        float accs[4];
#pragma unroll
        for (int m = 0; m < 4; ++m) {         // FULL unroll: const indices only
            float a  = w[m][0] * h0.x;
            float bq = w[m][1] * h0.y;
            a  = fmaf(w[m][2],  h0.z, a);  bq = fmaf(w[m][3],  h0.w, bq);
            a  = fmaf(w[m][4],  h1.x, a);  bq = fmaf(w[m][5],  h1.y, bq);
            a  = fmaf(w[m][6],  h1.z, a);  bq = fmaf(w[m][7],  h1.w, bq);
            a  = fmaf(w[m][8],  h2.x, a);  bq = fmaf(w[m][9],  h2.y, bq);
            a  = fmaf(w[m][10], h2.z, a);  bq = fmaf(w[m][11], h2.w, bq);
            a  = fmaf(w[m][12], h3.x, a);  bq = fmaf(w[m][13], h3.y, bq);
            a  = fmaf(w[m][14], h3.z, a);  bq = fmaf(w[m][15], h3.w, bq);
            accs[m] = a + bq;
        }

        // Partials: [g*264 + m*64 + lane], lane-stride 1 -> min 2-way (free).
        float* pb = &pbuf[cur][g * 264 + lane];
        pb[0]   = accs[0];
        pb[64]  = accs[1];
        pb[128] = accs[2];
        pb[192] = accs[3];

        // ONE barrier: drain LDS only; global prefetch/stores keep flying.
        asm volatile("s_waitcnt lgkmcnt(0)\n\ts_barrier" ::: "memory");

        // ---- reduce (all 64 lanes): partials of waves {q,q+4,q+8,q+12} ----
        const float* pr = &pbuf[cur][q * 264 + redoff];
        float s = (pr[0] + pr[1056]) + (pr[2112] + pr[3168]);
        s += __shfl_xor(s, 16);
        s += __shfl_xor(s, 32);

        hj = fmaxf(fmaf(OMA_F, hj, ALPHA_F * (s + pcur)), 0.f);
        if (lane < 16) {
            op[0] = hj;            // fire-and-forget
            hbuf[rrow] = hj;       // wave-private publish, read next iter
        }
        op += (size_t)BATCH * HID;
        pcur = pn1; pn1 = pn2;
    }

    if (lane < 16) {
        out[(size_t)T_STEPS * BATCH * HID + (size_t)b * HID + rrow] = hj;
    }
}

// ---------------------------------------------------------------------------
// Fallback (ws too small): R2's monolithic kernel (known-good 567 us).
// ---------------------------------------------------------------------------
__global__ __launch_bounds__(512, 2)
void ctrnn_mono(const float* __restrict__ x, const float* __restrict__ hidden,
                const float* __restrict__ noise, const float* __restrict__ W_in,
                const float* __restrict__ b_in, const float* __restrict__ W_hh,
                const float* __restrict__ b_hh, float* __restrict__ out)
{
    const int tid  = threadIdx.x;
    const int j    = tid & (HID - 1);
    const int half = tid >> 8;
    const int b    = blockIdx.x;

    __shared__ __align__(16) float hbuf[2][HID];
    __shared__ __align__(16) float xbuf[2][INSZ];
    __shared__ __align__(16) float pbuf[HID];

    float whh[128];
    const float* wrow = &W_hh[j * HID + half * 128];
#pragma unroll
    for (int k = 0; k < 128; k += 4) {
        float4 v = *reinterpret_cast<const float4*>(&wrow[k]);
        whh[k] = v.x; whh[k+1] = v.y; whh[k+2] = v.z; whh[k+3] = v.w;
    }
    float win[32];
    const float* wirow = &W_in[j * INSZ + half * 32];
#pragma unroll
    for (int k = 0; k < 32; k += 4) {
        float4 v = *reinterpret_cast<const float4*>(&wirow[k]);
        win[k] = v.x; win[k+1] = v.y; win[k+2] = v.z; win[k+3] = v.w;
    }

    float bias = 0.f, hj = 0.f, noise_j = 0.f;
    if (half == 0) {
        bias = b_in[j] + b_hh[j];
        hj = hidden[b * HID + j];
        hbuf[0][j] = hj;
        noise_j = noise[j];
        if (j < INSZ / 4) {
            *reinterpret_cast<float4*>(&xbuf[0][4 * j]) =
                *reinterpret_cast<const float4*>(&x[(size_t)b * INSZ + 4 * j]);
        }
    }
    __syncthreads();

    const int hoff = half * 128;
    const int ioff = half * 32;
    int cur = 0;
#pragma unroll 1
    for (int t = 0; t < T_STEPS; ++t) {
        float4 xnext = make_float4(0.f, 0.f, 0.f, 0.f);
        float  nnext = 0.f;
        if (half == 1) {
            if (j < INSZ / 4 && t + 1 < T_STEPS) {
                xnext = *reinterpret_cast<const float4*>(
                    &x[((size_t)(t + 1) * BATCH + b) * INSZ + 4 * j]);
            }
        } else if (t + 1 < T_STEPS) {
            nnext = noise[(t + 1) * HID + j];
        }

        float a0 = 0.f, a1 = 0.f, a2 = 0.f, a3 = 0.f;
#pragma unroll
        for (int k = 0; k < 128; k += 4) {
            float4 hv = *reinterpret_cast<const float4*>(&hbuf[cur][hoff + k]);
            a0 = fmaf(whh[k],     hv.x, a0);
            a1 = fmaf(whh[k + 1], hv.y, a1);
            a2 = fmaf(whh[k + 2], hv.z, a2);
            a3 = fmaf(whh[k + 3], hv.w, a3);
        }
#pragma unroll
        for (int k = 0; k < 32; k += 4) {
            float4 xv = *reinterpret_cast<const float4*>(&xbuf[cur][ioff + k]);
            a0 = fmaf(win[k],     xv.x, a0);
            a1 = fmaf(win[k + 1], xv.y, a1);
            a2 = fmaf(win[k + 2], xv.z, a2);
            a3 = fmaf(win[k + 3], xv.w, a3);
        }
        const float acc = (a0 + a1) + (a2 + a3);

        if (half == 1) pbuf[j] = acc;
        __syncthreads();

        const int nxt = cur ^ 1;
        if (half == 0) {
            const float pre = acc + pbuf[j] + bias + noise_j;
            hj = fmaxf(fmaf(OMA_F, hj, ALPHA_F * pre), 0.f);
            out[((size_t)t * BATCH + b) * HID + j] = hj;
            hbuf[nxt][j] = hj;
            noise_j = nnext;
        } else if (j < INSZ / 4 && t + 1 < T_STEPS) {
            *reinterpret_cast<float4*>(&xbuf[nxt][4 * j]) = xnext;
        }
        __syncthreads();
        cur = nxt;
    }

    if (half == 0) {
        out[(size_t)T_STEPS * BATCH * HID + (size_t)b * HID + j] = hj;
    }
}

extern "C" void kernel_launch(void* const* d_in, const int* in_sizes, int n_in,
                              void* d_out, int out_size, void* d_ws, size_t ws_size,
                              hipStream_t stream) {
    const float* x      = (const float*)d_in[0];
    const float* hidden = (const float*)d_in[1];
    const float* noise  = (const float*)d_in[2];
    const float* W_in   = (const float*)d_in[3];
    const float* b_in   = (const float*)d_in[4];
    const float* W_hh   = (const float*)d_in[5];
    const float* b_hh   = (const float*)d_in[6];
    float* out = (float*)d_out;

    const size_t prex_bytes = (size_t)T_STEPS * BATCH * HID * sizeof(float);
    if (ws_size >= prex_bytes) {
        float* prex = (float*)d_ws;
        hipLaunchKernelGGL(ctrnn_prex2, dim3(1024), dim3(256), 0, stream,
                           x, noise, W_in, b_in, b_hh, prex);
        hipLaunchKernelGGL(ctrnn_rec2, dim3(BATCH), dim3(1024), 0, stream,
                           hidden, prex, W_hh, out);
    } else {
        hipLaunchKernelGGL(ctrnn_mono, dim3(BATCH), dim3(512), 0, stream,
                           x, hidden, noise, W_in, b_in, W_hh, b_hh, out);
    }
}

// Round 4
// 1376.185 us; speedup vs baseline: 1.0688x; 1.0688x over previous
//
#include <hip/hip_runtime.h>

// CTRNN: T=512, B=256, I=64, H=256.
//   pre = x_t @ W_in^T + b_in + h @ W_hh^T + b_hh + noise_t
//   h   = max(0.8*h + 0.2*pre, 0)
//
// R3 post-mortem: both kernels got VGPR_Count=64 vs ~85-90 live floats ->
// w[] spilled to SCRATCH. prex2: FETCH 2.93 GB (91 B/thread/iter of spill
// reloads, 8 MB/XCD scratch > 4 MB L2 -> HBM thrash), dur 880us, VALUBusy 8%.
// rec2: scratch ~ L2-resident -> ~563us. Root cause: __launch_bounds__ 2nd
// arg is only a MIN waves/EU; backend greedily targets 8 waves/EU (64 VGPR)
// and spills to get there.
// R4 fix (single lever): pin occupancy with amdgpu_waves_per_eu(4,4) ->
// allocator must fit exactly 4 waves/EU, budget 512/4 = 128 VGPRs, no
// spill-for-occupancy. Structure unchanged from R3 (field-verified correct).
//
//  K1 ctrnn_prex2: prex[p,j] = x[p,:]&W_in[j,:] + b_in[j]+b_hh[j]+noise[t,j]
//     1024 blocks x 256 thr; W_in row in 64 regs; x staged in 32-pair LDS
//     chunks -> 8 barriers/block total.
//  K2 ctrnn_rec2:
//     - wave g owns h rows [16g,16g+16) AND k-chunk [16g,16g+16) -> h is
//       wave-private, no barrier needed for it.
//     - ONE barrier/step: lgkmcnt(0)-only asm barrier (global prefetches and
//       out stores stay in flight across it; __syncthreads would vmcnt-drain).
//     - pbuf double-buffered (stride 264: 2-way max on reduce reads = free).
//     - 64-lane spread reduce: 4 LDS reads + 2 shfl_xor.
//     - weights w[4][16] = 64 floats, FULLY const-indexed.

#define T_STEPS 512
#define BATCH   256
#define INSZ    64
#define HID     256
#define ALPHA_F 0.2f
#define OMA_F   0.8f

// ---------------------------------------------------------------------------
// Kernel 1: prex = x @ W_in^T + b_in + b_hh + noise(t)   [biases folded]
// 1024 blocks x 256 threads; block bb owns pairs [128*bb, 128*bb+128),
// t = (128*bb)>>8 is FIXED per block -> bias+noise folded once.
// ---------------------------------------------------------------------------
__global__ __launch_bounds__(256)
__attribute__((amdgpu_waves_per_eu(4, 4)))   // pin 4 waves/EU -> 128 VGPR, no spill
void ctrnn_prex2(const float* __restrict__ x,      // [T, B, I]
                 const float* __restrict__ noise,  // [T, H]
                 const float* __restrict__ W_in,   // [H, I]
                 const float* __restrict__ b_in,   // [H]
                 const float* __restrict__ b_hh,   // [H]
                 float* __restrict__ prex)         // [T, B, H] (ws)
{
    const int j  = threadIdx.x;          // output column 0..255
    const int bb = blockIdx.x;           // 0..1023
    const int p0 = bb * 128;
    const int t  = p0 >> 8;              // fixed per block

    __shared__ __align__(16) float xs[2][32][INSZ];   // 16 KB double-buffered

    float w[INSZ];
#pragma unroll
    for (int k = 0; k < INSZ; k += 4) {
        float4 v = *reinterpret_cast<const float4*>(&W_in[j * INSZ + k]);
        w[k] = v.x; w[k+1] = v.y; w[k+2] = v.z; w[k+3] = v.w;
    }
    const float bias = b_in[j] + b_hh[j] + noise[t * HID + j];

    // stage chunk 0: 32 pairs x 64 floats = 512 float4, 2 per thread, coalesced
    {
        const float4* s4 = reinterpret_cast<const float4*>(&x[(size_t)p0 * INSZ]);
        float4* d4 = reinterpret_cast<float4*>(&xs[0][0][0]);
        d4[j] = s4[j]; d4[j + 256] = s4[j + 256];
    }
    __syncthreads();

#pragma unroll 1
    for (int c = 0; c < 4; ++c) {
        const int cur = c & 1;

        // T14 split: issue next chunk's global loads now, LDS-write after compute
        float4 st0 = make_float4(0.f,0.f,0.f,0.f), st1 = st0;
        if (c < 3) {
            const float4* s4 = reinterpret_cast<const float4*>(
                &x[(size_t)(p0 + (c + 1) * 32) * INSZ]);
            st0 = s4[j]; st1 = s4[j + 256];
        }

        float* op = &prex[(size_t)(p0 + c * 32) * HID + j];
#pragma unroll 2
        for (int pp = 0; pp < 32; ++pp) {
            float a0 = 0.f, a1 = 0.f, a2 = 0.f, a3 = 0.f;
#pragma unroll
            for (int k = 0; k < INSZ; k += 4) {   // FULL unroll: w[] const-indexed
                float4 xv = *reinterpret_cast<const float4*>(&xs[cur][pp][k]);
                a0 = fmaf(w[k],     xv.x, a0);
                a1 = fmaf(w[k + 1], xv.y, a1);
                a2 = fmaf(w[k + 2], xv.z, a2);
                a3 = fmaf(w[k + 3], xv.w, a3);
            }
            op[(size_t)pp * HID] = (a0 + a1) + (a2 + a3) + bias;   // coalesced
        }

        if (c < 3) {
            float4* d4 = reinterpret_cast<float4*>(&xs[cur ^ 1][0][0]);
            d4[j] = st0; d4[j + 256] = st1;
        }
        __syncthreads();
    }
}

// ---------------------------------------------------------------------------
// Kernel 2: the recurrence. 256 blocks x 1024 threads (16 waves = 4/EU).
// ---------------------------------------------------------------------------
__global__ __launch_bounds__(1024)
__attribute__((amdgpu_waves_per_eu(4, 4)))   // pin 4 waves/EU -> 128 VGPR, no spill
void ctrnn_rec2(const float* __restrict__ hidden,  // [B, H]
                const float* __restrict__ prex,    // [T, B, H] (ws, biases in)
                const float* __restrict__ W_hh,    // [H, H]
                float* __restrict__ out)           // [T,B,H] ++ [B,H]
{
    const int tid  = threadIdx.x;
    const int lane = tid & 63;
    const int g    = tid >> 6;           // wave 0..15: rows & k-chunk [16g,16g+16)
    const int b    = blockIdx.x;

    __shared__ __align__(16) float hbuf[HID];
    __shared__ __align__(16) float pbuf[2][16 * 264];  // [buf][gg*264 + m*64 + jj]

    // W_hh: 4 rows x 16 k = 64 floats, FULLY const-indexed.
    float w[4][16];
#pragma unroll
    for (int m = 0; m < 4; ++m) {
        const float* wr = &W_hh[(lane + 64 * m) * HID + 16 * g];
#pragma unroll
        for (int c = 0; c < 4; ++c) {
            float4 v = *reinterpret_cast<const float4*>(&wr[4 * c]);
            w[m][4*c]   = v.x; w[m][4*c+1] = v.y;
            w[m][4*c+2] = v.z; w[m][4*c+3] = v.w;
        }
    }

    const int rrow = 16 * g + (lane & 15);   // row this lane reduces/updates
    float hj = hidden[b * HID + rrow];

    // prex pointer chain, 2-deep prefetch. Lanes replicated x4 by q read the
    // same 16 addresses -> coalesced into one 64B request, no extra traffic.
    const float* pp = &prex[(size_t)b * HID + rrow];
    float pcur = pp[0];                       // t = 0
    float pn1  = pp[BATCH * HID];             // t = 1
    pp += 2 * (size_t)BATCH * HID;
    float* op = &out[(size_t)b * HID + rrow];

    if (lane < 16) hbuf[rrow] = hj;           // wave-private h init
    __syncthreads();

    const int redoff = ((g >> 2) << 6) + ((g & 3) << 4) + (lane & 15);
    const int q = lane >> 4;

#pragma unroll 1
    for (int t = 0; t < T_STEPS; ++t) {
        const int cur = t & 1;

        // prefetch prex(t+2): stays in flight across the lgkm-only barrier
        float pn2 = 0.f;
        if (t + 2 < T_STEPS) pn2 = pp[0];
        pp += (size_t)BATCH * HID;

        // ---- FMA phase: h chunk is wave-private (written last step) ----
        const float4 h0 = *reinterpret_cast<const float4*>(&hbuf[16 * g]);
        const float4 h1 = *reinterpret_cast<const float4*>(&hbuf[16 * g + 4]);
        const float4 h2 = *reinterpret_cast<const float4*>(&hbuf[16 * g + 8]);
        const float4 h3 = *reinterpret_cast<const float4*>(&hbuf[16 * g + 12]);

        float accs[4];
#pragma unroll
        for (int m = 0; m < 4; ++m) {         // FULL unroll: const indices only
            float a  = w[m][0] * h0.x;
            float bq = w[m][1] * h0.y;
            a  = fmaf(w[m][2],  h0.z, a);  bq = fmaf(w[m][3],  h0.w, bq);
            a  = fmaf(w[m][4],  h1.x, a);  bq = fmaf(w[m][5],  h1.y, bq);
            a  = fmaf(w[m][6],  h1.z, a);  bq = fmaf(w[m][7],  h1.w, bq);
            a  = fmaf(w[m][8],  h2.x, a);  bq = fmaf(w[m][9],  h2.y, bq);
            a  = fmaf(w[m][10], h2.z, a);  bq = fmaf(w[m][11], h2.w, bq);
            a  = fmaf(w[m][12], h3.x, a);  bq = fmaf(w[m][13], h3.y, bq);
            a  = fmaf(w[m][14], h3.z, a);  bq = fmaf(w[m][15], h3.w, bq);
            accs[m] = a + bq;
        }

        // Partials: [g*264 + m*64 + lane], lane-stride 1 -> min 2-way (free).
        float* pb = &pbuf[cur][g * 264 + lane];
        pb[0]   = accs[0];
        pb[64]  = accs[1];
        pb[128] = accs[2];
        pb[192] = accs[3];

        // ONE barrier: drain LDS only; global prefetch/stores keep flying.
        asm volatile("s_waitcnt lgkmcnt(0)\n\ts_barrier" ::: "memory");

        // ---- reduce (all 64 lanes): partials of waves {q,q+4,q+8,q+12} ----
        const float* pr = &pbuf[cur][q * 264 + redoff];
        float s = (pr[0] + pr[1056]) + (pr[2112] + pr[3168]);
        s += __shfl_xor(s, 16);
        s += __shfl_xor(s, 32);

        hj = fmaxf(fmaf(OMA_F, hj, ALPHA_F * (s + pcur)), 0.f);
        if (lane < 16) {
            op[0] = hj;            // fire-and-forget
            hbuf[rrow] = hj;       // wave-private publish, read next iter
        }
        op += (size_t)BATCH * HID;
        pcur = pn1; pn1 = pn2;
    }

    if (lane < 16) {
        out[(size_t)T_STEPS * BATCH * HID + (size_t)b * HID + rrow] = hj;
    }
}

// ---------------------------------------------------------------------------
// Fallback (ws too small): prior session's monolithic kernel (known-good).
// ---------------------------------------------------------------------------
__global__ __launch_bounds__(512, 2)
void ctrnn_mono(const float* __restrict__ x, const float* __restrict__ hidden,
                const float* __restrict__ noise, const float* __restrict__ W_in,
                const float* __restrict__ b_in, const float* __restrict__ W_hh,
                const float* __restrict__ b_hh, float* __restrict__ out)
{
    const int tid  = threadIdx.x;
    const int j    = tid & (HID - 1);
    const int half = tid >> 8;
    const int b    = blockIdx.x;

    __shared__ __align__(16) float hbuf[2][HID];
    __shared__ __align__(16) float xbuf[2][INSZ];
    __shared__ __align__(16) float pbuf[HID];

    float whh[128];
    const float* wrow = &W_hh[j * HID + half * 128];
#pragma unroll
    for (int k = 0; k < 128; k += 4) {
        float4 v = *reinterpret_cast<const float4*>(&wrow[k]);
        whh[k] = v.x; whh[k+1] = v.y; whh[k+2] = v.z; whh[k+3] = v.w;
    }
    float win[32];
    const float* wirow = &W_in[j * INSZ + half * 32];
#pragma unroll
    for (int k = 0; k < 32; k += 4) {
        float4 v = *reinterpret_cast<const float4*>(&wirow[k]);
        win[k] = v.x; win[k+1] = v.y; win[k+2] = v.z; win[k+3] = v.w;
    }

    float bias = 0.f, hj = 0.f, noise_j = 0.f;
    if (half == 0) {
        bias = b_in[j] + b_hh[j];
        hj = hidden[b * HID + j];
        hbuf[0][j] = hj;
        noise_j = noise[j];
        if (j < INSZ / 4) {
            *reinterpret_cast<float4*>(&xbuf[0][4 * j]) =
                *reinterpret_cast<const float4*>(&x[(size_t)b * INSZ + 4 * j]);
        }
    }
    __syncthreads();

    const int hoff = half * 128;
    const int ioff = half * 32;
    int cur = 0;
#pragma unroll 1
    for (int t = 0; t < T_STEPS; ++t) {
        float4 xnext = make_float4(0.f, 0.f, 0.f, 0.f);
        float  nnext = 0.f;
        if (half == 1) {
            if (j < INSZ / 4 && t + 1 < T_STEPS) {
                xnext = *reinterpret_cast<const float4*>(
                    &x[((size_t)(t + 1) * BATCH + b) * INSZ + 4 * j]);
            }
        } else if (t + 1 < T_STEPS) {
            nnext = noise[(t + 1) * HID + j];
        }

        float a0 = 0.f, a1 = 0.f, a2 = 0.f, a3 = 0.f;
#pragma unroll
        for (int k = 0; k < 128; k += 4) {
            float4 hv = *reinterpret_cast<const float4*>(&hbuf[cur][hoff + k]);
            a0 = fmaf(whh[k],     hv.x, a0);
            a1 = fmaf(whh[k + 1], hv.y, a1);
            a2 = fmaf(whh[k + 2], hv.z, a2);
            a3 = fmaf(whh[k + 3], hv.w, a3);
        }
#pragma unroll
        for (int k = 0; k < 32; k += 4) {
            float4 xv = *reinterpret_cast<const float4*>(&xbuf[cur][ioff + k]);
            a0 = fmaf(win[k],     xv.x, a0);
            a1 = fmaf(win[k + 1], xv.y, a1);
            a2 = fmaf(win[k + 2], xv.z, a2);
            a3 = fmaf(win[k + 3], xv.w, a3);
        }
        const float acc = (a0 + a1) + (a2 + a3);

        if (half == 1) pbuf[j] = acc;
        __syncthreads();

        const int nxt = cur ^ 1;
        if (half == 0) {
            const float pre = acc + pbuf[j] + bias + noise_j;
            hj = fmaxf(fmaf(OMA_F, hj, ALPHA_F * pre), 0.f);
            out[((size_t)t * BATCH + b) * HID + j] = hj;
            hbuf[nxt][j] = hj;
            noise_j = nnext;
        } else if (j < INSZ / 4 && t + 1 < T_STEPS) {
            *reinterpret_cast<float4*>(&xbuf[nxt][4 * j]) = xnext;
        }
        __syncthreads();
        cur = nxt;
    }

    if (half == 0) {
        out[(size_t)T_STEPS * BATCH * HID + (size_t)b * HID + j] = hj;
    }
}

extern "C" void kernel_launch(void* const* d_in, const int* in_sizes, int n_in,
                              void* d_out, int out_size, void* d_ws, size_t ws_size,
                              hipStream_t stream) {
    const float* x      = (const float*)d_in[0];
    const float* hidden = (const float*)d_in[1];
    const float* noise  = (const float*)d_in[2];
    const float* W_in   = (const float*)d_in[3];
    const float* b_in   = (const float*)d_in[4];
    const float* W_hh   = (const float*)d_in[5];
    const float* b_hh   = (const float*)d_in[6];
    float* out = (float*)d_out;

    const size_t prex_bytes = (size_t)T_STEPS * BATCH * HID * sizeof(float);
    if (ws_size >= prex_bytes) {
        float* prex = (float*)d_ws;
        hipLaunchKernelGGL(ctrnn_prex2, dim3(1024), dim3(256), 0, stream,
                           x, noise, W_in, b_in, b_hh, prex);
        hipLaunchKernelGGL(ctrnn_rec2, dim3(BATCH), dim3(1024), 0, stream,
                           hidden, prex, W_hh, out);
    } else {
        hipLaunchKernelGGL(ctrnn_mono, dim3(BATCH), dim3(512), 0, stream,
                           x, hidden, noise, W_in, b_in, W_hh, b_hh, out);
    }
}

// Round 5
// 557.283 us; speedup vs baseline: 2.6393x; 2.4695x over previous
//
#include <hip/hip_runtime.h>

// CTRNN: T=512, B=256, I=64, H=256.
//   pre = x_t @ W_in^T + b_in + h @ W_hh^T + b_hh + noise_t
//   h   = max(0.8*h + 0.2*pre, 0)
//
// R4 post-mortem: amdgpu_waves_per_eu(4,4) did NOT raise the VGPR budget
// (VGPR_Count=64 again, FETCH 2.89 GB spill traffic identical). Two rounds
// of fighting the allocator lost. R5: design UNDER the 64-VGPR cap.
//  - ctrnn_rec: reverted VERBATIM to R0's kernel (field-measured 376us,
//    VGPR=48, VALUBusy 77%, 0 bank conflicts). Untouched this round.
//  - ctrnn_prex3: new. <=~55 live floats/thread so 64 VGPRs never spill:
//    * in-wave k-half split: lanes 0-31 / 32-63 cover the SAME 32 columns
//      with k in [0,32) / [32,64); each thread holds w[32] only; halves
//      combine with one __shfl_xor(s,32); hf==0 lanes store (128B/wave,
//      coalesced). No cross-wave partials -> no extra barriers.
//    * x read from LDS at UNIFORM address per 32-lane half -> broadcast,
//      conflict-free (m136: same-address = no conflict).
//    * 512 thr/block, 256 pairs/block staged as 8 x 32-pair double-buffered
//      chunks -> 8 __syncthreads per block total (R0 prex had 128 -> 237us).
//    * t = blockIdx.x is FIXED per block -> noise folded into bias once.

#define T_STEPS 512
#define BATCH   256
#define INSZ    64
#define HID     256
#define ALPHA_F 0.2f
#define OMA_F   0.8f

// ---------------------------------------------------------------------------
// Kernel 1: prex = x @ W_in^T + b_in + b_hh + noise(t)   [biases folded]
// 512 blocks x 512 threads. Block bb owns pairs [256*bb, 256*bb+256) == all
// of batch for t = bb. Wave wv covers cols [32*wv, 32*wv+32); lane&31 = col,
// lane>>5 = k-half.
// ---------------------------------------------------------------------------
__global__ __launch_bounds__(512, 2)
void ctrnn_prex3(const float* __restrict__ x,      // [T, B, I]
                 const float* __restrict__ noise,  // [T, H]
                 const float* __restrict__ W_in,   // [H, I]
                 const float* __restrict__ b_in,   // [H]
                 const float* __restrict__ b_hh,   // [H]
                 float* __restrict__ prex)         // [T, B, H] (ws)
{
    const int tid  = threadIdx.x;
    const int lane = tid & 63;
    const int wv   = tid >> 6;          // 0..7 -> column group
    const int cl   = lane & 31;         // col within group
    const int hf   = lane >> 5;         // k-half: 0 -> [0,32), 1 -> [32,64)
    const int col  = wv * 32 + cl;      // 0..255
    const int bb   = blockIdx.x;        // == t (256 pairs per block)
    const int p0   = bb * 256;

    __shared__ __align__(16) float xs[2][32][INSZ];   // 8 KB x 2, dbuf

    // w[32]: this thread's k-half of W_in row `col`. 32 + ~20 misc live
    // floats -> fits 64 VGPRs with slack (the R3/R4 spill demon needs ~85).
    float w[32];
    {
        const float* wr = &W_in[col * INSZ + hf * 32];
#pragma unroll
        for (int k = 0; k < 32; k += 4) {
            float4 v = *reinterpret_cast<const float4*>(&wr[k]);
            w[k] = v.x; w[k+1] = v.y; w[k+2] = v.z; w[k+3] = v.w;
        }
    }
    const float bias = b_in[col] + b_hh[col] + noise[bb * HID + col];

    // stage chunk 0: 32 pairs x 64 floats = 512 float4, 1 per thread.
    {
        const float4* s4 = reinterpret_cast<const float4*>(&x[(size_t)p0 * INSZ]);
        reinterpret_cast<float4*>(&xs[0][0][0])[tid] = s4[tid];
    }
    __syncthreads();

    const int khf = hf * 32;
#pragma unroll 1
    for (int c = 0; c < 8; ++c) {                 // 8 chunks x 32 pairs
        const int cur = c & 1;

        // issue next chunk's global load early; LDS-write after compute
        float4 st = make_float4(0.f, 0.f, 0.f, 0.f);
        if (c < 7) {
            st = reinterpret_cast<const float4*>(
                &x[(size_t)(p0 + (c + 1) * 32) * INSZ])[tid];
        }

        float* op = &prex[(size_t)(p0 + c * 32) * HID + col];
#pragma unroll 2
        for (int pp = 0; pp < 32; ++pp) {
            // 8 broadcast b128 reads (uniform addr per 32-lane half).
            float a0 = 0.f, a1 = 0.f, a2 = 0.f, a3 = 0.f;
#pragma unroll
            for (int k = 0; k < 32; k += 4) {     // FULL unroll, const idx
                float4 xv = *reinterpret_cast<const float4*>(&xs[cur][pp][khf + k]);
                a0 = fmaf(w[k],     xv.x, a0);
                a1 = fmaf(w[k + 1], xv.y, a1);
                a2 = fmaf(w[k + 2], xv.z, a2);
                a3 = fmaf(w[k + 3], xv.w, a3);
            }
            float s = (a0 + a1) + (a2 + a3);
            s += __shfl_xor(s, 32);               // combine k-halves in-wave
            if (hf == 0) {
                op[(size_t)pp * HID] = s + bias;  // 32 lanes x 4B = 128B coalesced
            }
        }

        if (c < 7) {
            reinterpret_cast<float4*>(&xs[cur ^ 1][0][0])[tid] = st;
        }
        __syncthreads();                          // 8 per block total
    }
}

// ---------------------------------------------------------------------------
// Kernel 2: the recurrence. R0-VERBATIM (field-measured 376us, VGPR=48).
// 256 blocks (1/batch) x 1024 threads (4 waves/SIMD).
// Thread (g=tid>>6, jj=tid&63): rows {jj+64m, m=0..3}, k in [16g,16g+16).
// 4x row-reuse: read h-chunk once (4 broadcast ds_read_b128), 64 FMAs.
// Partials -> pbuf[16][256] (conflict-free); tid<256 reduce + update.
// prex prefetched 2 steps deep to cover HBM latency.
// ---------------------------------------------------------------------------
__global__ __launch_bounds__(1024, 4)
void ctrnn_rec(const float* __restrict__ hidden,  // [B, H]
               const float* __restrict__ prex,    // [T, B, H] (ws)
               const float* __restrict__ W_hh,    // [H, H]
               float* __restrict__ out)           // [T,B,H] ++ [B,H]
{
    const int tid = threadIdx.x;
    const int jj  = tid & 63;            // lane  -> row offset
    const int g   = tid >> 6;            // 0..15 -> k-chunk, wave-uniform
    const int b   = blockIdx.x;

    __shared__ __align__(16) float hbuf[2][HID];
    __shared__ __align__(16) float pbuf[16][HID];

    // Weights: 4 rows x 16 k = 64 floats, FULLY const-indexed -> arch VGPRs.
    float w[4][16];
#pragma unroll
    for (int m = 0; m < 4; ++m) {
        const float* wrow = &W_hh[(jj + 64 * m) * HID + 16 * g];
#pragma unroll
        for (int c = 0; c < 4; ++c) {
            float4 v = *reinterpret_cast<const float4*>(&wrow[4 * c]);
            w[m][4*c]   = v.x; w[m][4*c+1] = v.y;
            w[m][4*c+2] = v.z; w[m][4*c+3] = v.w;
        }
    }

    float hj = 0.f, pcur = 0.f, pn1 = 0.f;
    if (tid < HID) {                     // reduce/update threads: row r = tid
        hj = hidden[b * HID + tid];
        hbuf[0][tid] = hj;
        pcur = prex[(size_t)b * HID + tid];                       // t=0
        pn1  = prex[((size_t)1 * BATCH + b) * HID + tid];         // t=1
    }
    __syncthreads();

    const int koff = 16 * g;
    int cur = 0;
#pragma unroll 1
    for (int t = 0; t < T_STEPS; ++t) {
        // 2-deep prefetch: issue load for t+2 at the top (max latency cover).
        float pn2 = 0.f;
        if (tid < HID && t + 2 < T_STEPS) {
            pn2 = prex[((size_t)(t + 2) * BATCH + b) * HID + tid];
        }

        // h-chunk read ONCE (4 broadcast b128), reused across 4 rows.
        float4 h0 = *reinterpret_cast<const float4*>(&hbuf[cur][koff]);
        float4 h1 = *reinterpret_cast<const float4*>(&hbuf[cur][koff + 4]);
        float4 h2 = *reinterpret_cast<const float4*>(&hbuf[cur][koff + 8]);
        float4 h3 = *reinterpret_cast<const float4*>(&hbuf[cur][koff + 12]);

        float acc[4];
#pragma unroll
        for (int m = 0; m < 4; ++m) {
            float a = 0.f, bq = 0.f;
            a  = fmaf(w[m][0],  h0.x, a);  bq = fmaf(w[m][1],  h0.y, bq);
            a  = fmaf(w[m][2],  h0.z, a);  bq = fmaf(w[m][3],  h0.w, bq);
            a  = fmaf(w[m][4],  h1.x, a);  bq = fmaf(w[m][5],  h1.y, bq);
            a  = fmaf(w[m][6],  h1.z, a);  bq = fmaf(w[m][7],  h1.w, bq);
            a  = fmaf(w[m][8],  h2.x, a);  bq = fmaf(w[m][9],  h2.y, bq);
            a  = fmaf(w[m][10], h2.z, a);  bq = fmaf(w[m][11], h2.w, bq);
            a  = fmaf(w[m][12], h3.x, a);  bq = fmaf(w[m][13], h3.y, bq);
            a  = fmaf(w[m][14], h3.z, a);  bq = fmaf(w[m][15], h3.w, bq);
            acc[m] = a + bq;
        }
        // Conflict-free partial writes (lanes -> consecutive rows).
        pbuf[g][jj]       = acc[0];
        pbuf[g][jj + 64]  = acc[1];
        pbuf[g][jj + 128] = acc[2];
        pbuf[g][jj + 192] = acc[3];
        __syncthreads();                 // partials visible; hbuf[cur] done

        const int nxt = cur ^ 1;
        if (tid < HID) {
            float s = pcur;
#pragma unroll
            for (int gg = 0; gg < 16; ++gg) s += pbuf[gg][tid];
            hj = fmaxf(fmaf(OMA_F, hj, ALPHA_F * s), 0.f);
            out[((size_t)t * BATCH + b) * HID + tid] = hj;   // coalesced 1 KB
            hbuf[nxt][tid] = hj;
            pcur = pn1; pn1 = pn2;
        }
        __syncthreads();                 // hbuf[nxt] published
        cur = nxt;
    }

    if (tid < HID) {
        out[(size_t)T_STEPS * BATCH * HID + (size_t)b * HID + tid] = hj;
    }
}

// ---------------------------------------------------------------------------
// Fallback (ws too small): monolithic kernel (known-good).
// ---------------------------------------------------------------------------
__global__ __launch_bounds__(512, 2)
void ctrnn_mono(const float* __restrict__ x, const float* __restrict__ hidden,
                const float* __restrict__ noise, const float* __restrict__ W_in,
                const float* __restrict__ b_in, const float* __restrict__ W_hh,
                const float* __restrict__ b_hh, float* __restrict__ out)
{
    const int tid  = threadIdx.x;
    const int j    = tid & (HID - 1);
    const int half = tid >> 8;
    const int b    = blockIdx.x;

    __shared__ __align__(16) float hbuf[2][HID];
    __shared__ __align__(16) float xbuf[2][INSZ];
    __shared__ __align__(16) float pbuf[HID];

    float whh[128];
    const float* wrow = &W_hh[j * HID + half * 128];
#pragma unroll
    for (int k = 0; k < 128; k += 4) {
        float4 v = *reinterpret_cast<const float4*>(&wrow[k]);
        whh[k] = v.x; whh[k+1] = v.y; whh[k+2] = v.z; whh[k+3] = v.w;
    }
    float win[32];
    const float* wirow = &W_in[j * INSZ + half * 32];
#pragma unroll
    for (int k = 0; k < 32; k += 4) {
        float4 v = *reinterpret_cast<const float4*>(&wirow[k]);
        win[k] = v.x; win[k+1] = v.y; win[k+2] = v.z; win[k+3] = v.w;
    }

    float bias = 0.f, hj = 0.f, noise_j = 0.f;
    if (half == 0) {
        bias = b_in[j] + b_hh[j];
        hj = hidden[b * HID + j];
        hbuf[0][j] = hj;
        noise_j = noise[j];
        if (j < INSZ / 4) {
            *reinterpret_cast<float4*>(&xbuf[0][4 * j]) =
                *reinterpret_cast<const float4*>(&x[(size_t)b * INSZ + 4 * j]);
        }
    }
    __syncthreads();

    const int hoff = half * 128;
    const int ioff = half * 32;
    int cur = 0;
#pragma unroll 1
    for (int t = 0; t < T_STEPS; ++t) {
        float4 xnext = make_float4(0.f, 0.f, 0.f, 0.f);
        float  nnext = 0.f;
        if (half == 1) {
            if (j < INSZ / 4 && t + 1 < T_STEPS) {
                xnext = *reinterpret_cast<const float4*>(
                    &x[((size_t)(t + 1) * BATCH + b) * INSZ + 4 * j]);
            }
        } else if (t + 1 < T_STEPS) {
            nnext = noise[(t + 1) * HID + j];
        }

        float a0 = 0.f, a1 = 0.f, a2 = 0.f, a3 = 0.f;
#pragma unroll
        for (int k = 0; k < 128; k += 4) {
            float4 hv = *reinterpret_cast<const float4*>(&hbuf[cur][hoff + k]);
            a0 = fmaf(whh[k],     hv.x, a0);
            a1 = fmaf(whh[k + 1], hv.y, a1);
            a2 = fmaf(whh[k + 2], hv.z, a2);
            a3 = fmaf(whh[k + 3], hv.w, a3);
        }
#pragma unroll
        for (int k = 0; k < 32; k += 4) {
            float4 xv = *reinterpret_cast<const float4*>(&xbuf[cur][ioff + k]);
            a0 = fmaf(win[k],     xv.x, a0);
            a1 = fmaf(win[k + 1], xv.y, a1);
            a2 = fmaf(win[k + 2], xv.z, a2);
            a3 = fmaf(win[k + 3], xv.w, a3);
        }
        const float acc = (a0 + a1) + (a2 + a3);

        if (half == 1) pbuf[j] = acc;
        __syncthreads();

        const int nxt = cur ^ 1;
        if (half == 0) {
            const float pre = acc + pbuf[j] + bias + noise_j;
            hj = fmaxf(fmaf(OMA_F, hj, ALPHA_F * pre), 0.f);
            out[((size_t)t * BATCH + b) * HID + j] = hj;
            hbuf[nxt][j] = hj;
            noise_j = nnext;
        } else if (j < INSZ / 4 && t + 1 < T_STEPS) {
            *reinterpret_cast<float4*>(&xbuf[nxt][4 * j]) = xnext;
        }
        __syncthreads();
        cur = nxt;
    }

    if (half == 0) {
        out[(size_t)T_STEPS * BATCH * HID + (size_t)b * HID + j] = hj;
    }
}

extern "C" void kernel_launch(void* const* d_in, const int* in_sizes, int n_in,
                              void* d_out, int out_size, void* d_ws, size_t ws_size,
                              hipStream_t stream) {
    const float* x      = (const float*)d_in[0];
    const float* hidden = (const float*)d_in[1];
    const float* noise  = (const float*)d_in[2];
    const float* W_in   = (const float*)d_in[3];
    const float* b_in   = (const float*)d_in[4];
    const float* W_hh   = (const float*)d_in[5];
    const float* b_hh   = (const float*)d_in[6];
    float* out = (float*)d_out;

    const size_t prex_bytes = (size_t)T_STEPS * BATCH * HID * sizeof(float);
    if (ws_size >= prex_bytes) {
        float* prex = (float*)d_ws;
        hipLaunchKernelGGL(ctrnn_prex3, dim3(512), dim3(512), 0, stream,
                           x, noise, W_in, b_in, b_hh, prex);
        hipLaunchKernelGGL(ctrnn_rec, dim3(BATCH), dim3(1024), 0, stream,
                           hidden, prex, W_hh, out);
    } else {
        hipLaunchKernelGGL(ctrnn_mono, dim3(BATCH), dim3(512), 0, stream,
                           x, hidden, noise, W_in, b_in, W_hh, b_hh, out);
    }
}